// Round 6
// baseline (60.325 us; speedup 1.0000x reference)
//
#include <hip/hip_runtime.h>

// PointPillarsScatter: scatter (B,P,C) pillar features into a (B,C,NX,NY) BEV grid.
// Duplicate cells: reference scatter-set is last-write-wins over flattened (B*P)
// order => highest p wins per cell. Reproduced deterministically via atomicMax
// on a per-cell winner-index buffer, then a channel-blocked gather.
//
// R4/R5: (1) own vectorized winner-init kernel (replaces rocclr hipMemsetAsync);
// (2) nontemporal output stores (252 MB write stream bypasses L2/LLC, keeping
// caches for winner 3.9MB x4 reads + feats 12MB x1 read). R5 fix: the builtin
// needs a native clang vector type, not HIP's float4 class.

#define NXD 496
#define NYD 496
#define CD  64
#define BD  4
#define PD  12000
#define NXNY (NXD * NYD)
#define NY4 (NYD / 4)      // 124
#define CBLK 16            // channels per thread (one 64B feats cacheline)
#define NCB (CD / CBLK)    // 4 channel-blocks

typedef float fvec4 __attribute__((ext_vector_type(4)));  // native vector for nt-store

// Phase 1: winner[cell] = -1 for all B*NX*NY cells. int4 stores, 961 blocks.
__global__ void pp_init_winner(int* __restrict__ winner) {
    const int total4 = BD * NXNY / 4;              // 246,016
    int tid = blockIdx.x * blockDim.x + threadIdx.x;
    if (tid < total4) {
        reinterpret_cast<int4*>(winner)[tid] = make_int4(-1, -1, -1, -1);
    }
}

// Phase 2: each valid pillar claims its cell with atomicMax(p) -> last-wins.
__global__ void pp_scatter_idx(const int* __restrict__ coords,
                               int* __restrict__ winner) {
    int tid = blockIdx.x * blockDim.x + threadIdx.x;
    if (tid >= BD * PD) return;
    int b = tid / PD;
    int x = coords[tid * 3 + 1];
    int y = coords[tid * 3 + 2];
    bool valid = (x + y > 0) && (x >= 0) && (x < NXD) && (y >= 0) && (y < NYD);
    if (valid) {
        int p = tid - b * PD;
        atomicMax(&winner[b * NXNY + x * NYD + y], p);
    }
}

// Phase 3: one thread per {4 consecutive y-cells} x {16-channel block}.
// - 1 coalesced int4 winner read (whole winner buffer read only NCB=4 times)
// - per occupied cell (~4.7%): 4 aligned float4 feats loads = that cell's 64B
//   channel-slab; across the 4 c-blocks each pillar row is read exactly once
// - 16 coalesced nontemporal stores (wave = 1KB contiguous per store)
// Empty cells store zeros (doubles as output zero-init over poisoned d_out).
__global__ void pp_gather_out(const float* __restrict__ feats,
                              const int* __restrict__ winner,
                              float* __restrict__ out) {
    const int total = BD * NCB * NXD * NY4;        // 984,064
    int tid = blockIdx.x * blockDim.x + threadIdx.x;
    if (tid >= total) return;

    int y4 = tid % NY4;
    int r  = tid / NY4;
    int x  = r % NXD;  r /= NXD;
    int cb = r % NCB;
    int b  = r / NCB;

    const int4 w = *reinterpret_cast<const int4*>(
        &winner[b * NXNY + x * NYD + y4 * 4]);
    const int wa[4] = { w.x, w.y, w.z, w.w };

    float f[4][CBLK] = {};   // [cell][channel] — fully unrolled, stays in VGPRs

#pragma unroll
    for (int j = 0; j < 4; ++j) {
        if (wa[j] >= 0) {
            const float4* src = reinterpret_cast<const float4*>(
                feats + ((size_t)(b * PD + wa[j])) * CD + cb * CBLK);
            float4 a0 = src[0], a1 = src[1], a2 = src[2], a3 = src[3];
            f[j][0]  = a0.x; f[j][1]  = a0.y; f[j][2]  = a0.z; f[j][3]  = a0.w;
            f[j][4]  = a1.x; f[j][5]  = a1.y; f[j][6]  = a1.z; f[j][7]  = a1.w;
            f[j][8]  = a2.x; f[j][9]  = a2.y; f[j][10] = a2.z; f[j][11] = a2.w;
            f[j][12] = a3.x; f[j][13] = a3.y; f[j][14] = a3.z; f[j][15] = a3.w;
        }
    }

    // out[(b, cb*16 + c, x, y4*4 .. +3)], channel stride = NXNY floats.
    float* obase = out + (((size_t)(b * CD + cb * CBLK) * NXD + x) * NYD + y4 * 4);
#pragma unroll
    for (int c = 0; c < CBLK; ++c) {
        fvec4 v = { f[0][c], f[1][c], f[2][c], f[3][c] };
        __builtin_nontemporal_store(
            v, reinterpret_cast<fvec4*>(obase + (size_t)c * NXNY));
    }
}

extern "C" void kernel_launch(void* const* d_in, const int* in_sizes, int n_in,
                              void* d_out, int out_size, void* d_ws, size_t ws_size,
                              hipStream_t stream) {
    const float* feats  = (const float*)d_in[0];   // (B,P,C) fp32
    const int*   coords = (const int*)d_in[1];     // (B,P,3) int32
    float*       out    = (float*)d_out;           // (B,C,NX,NY) fp32
    int*         winner = (int*)d_ws;              // B*NX*NY int32 = 3,936,256 B

    const int init4 = BD * NXNY / 4;               // 246,016 int4 stores
    pp_init_winner<<<(init4 + 255) / 256, 256, 0, stream>>>(winner);

    pp_scatter_idx<<<(BD * PD + 255) / 256, 256, 0, stream>>>(coords, winner);

    const int total = BD * NCB * NXD * NY4;        // 984,064 threads
    pp_gather_out<<<(total + 255) / 256, 256, 0, stream>>>(feats, winner, out);
}

// Round 7
// 52.899 us; speedup vs baseline: 1.1404x; 1.1404x over previous
//
#include <hip/hip_runtime.h>

// PointPillarsScatter: scatter (B,P,C) pillar features into a (B,C,NX,NY) BEV grid.
// Duplicate cells: reference scatter-set is last-write-wins over flattened (B*P)
// order => highest p wins per cell. Reproduced deterministically via atomicMax
// on a per-cell winner-index buffer, then a channel-blocked gather.
//
// R6: (1) REVERT nontemporal stores (R5 post-mortem: nt write-around path is
// slower than the normal L2-aggregated write stream for full-line stores;
// 53.0 -> 60.3 us regression). (2) Loop all 4 channel-blocks inside one thread
// so the winner buffer is read once (15.7 MB -> 3.9 MB of winner traffic).

#define NXD 496
#define NYD 496
#define CD  64
#define BD  4
#define PD  12000
#define NXNY (NXD * NYD)
#define NY4 (NYD / 4)      // 124
#define CBLK 16            // channels per feats cacheline chunk (64B)
#define NCB (CD / CBLK)    // 4 channel-blocks

// Phase 1: winner[cell] = -1 for all B*NX*NY cells. int4 stores, 961 blocks.
__global__ void pp_init_winner(int* __restrict__ winner) {
    const int total4 = BD * NXNY / 4;              // 246,016
    int tid = blockIdx.x * blockDim.x + threadIdx.x;
    if (tid < total4) {
        reinterpret_cast<int4*>(winner)[tid] = make_int4(-1, -1, -1, -1);
    }
}

// Phase 2: each valid pillar claims its cell with atomicMax(p) -> last-wins.
__global__ void pp_scatter_idx(const int* __restrict__ coords,
                               int* __restrict__ winner) {
    int tid = blockIdx.x * blockDim.x + threadIdx.x;
    if (tid >= BD * PD) return;
    int b = tid / PD;
    int x = coords[tid * 3 + 1];
    int y = coords[tid * 3 + 2];
    bool valid = (x + y > 0) && (x >= 0) && (x < NXD) && (y >= 0) && (y < NYD);
    if (valid) {
        int p = tid - b * PD;
        atomicMax(&winner[b * NXNY + x * NYD + y], p);
    }
}

// Phase 3: one thread per {4 consecutive y-cells}, looping all 64 channels.
// - 1 coalesced int4 winner read per thread (winner read ONCE total: 3.9 MB)
// - per occupied cell (~4.7%): its full 256B feats row read exactly once,
//   as 4x float4 per channel-block iteration
// - 64 coalesced float4 stores (wave = 1KB contiguous per store instruction)
// Empty cells store zeros (doubles as output zero-init over poisoned d_out).
__global__ void pp_gather_out(const float* __restrict__ feats,
                              const int* __restrict__ winner,
                              float* __restrict__ out) {
    const int total = BD * NXD * NY4;              // 246,016
    int tid = blockIdx.x * blockDim.x + threadIdx.x;
    if (tid >= total) return;

    int y4 = tid % NY4;
    int r  = tid / NY4;
    int x  = r % NXD;
    int b  = r / NXD;

    const int4 w = *reinterpret_cast<const int4*>(
        &winner[b * NXNY + x * NYD + y4 * 4]);
    const int wa[4] = { w.x, w.y, w.z, w.w };

    const float* fb = feats + (size_t)b * PD * CD;
    // out[(b, c, x, y4*4 .. +3)], channel stride = NXNY floats.
    float* obase = out + (((size_t)b * CD * NXD + x) * NYD + y4 * 4);

#pragma unroll
    for (int cb = 0; cb < NCB; ++cb) {
        float f[4][CBLK] = {};   // static-indexed via full unroll -> VGPRs

#pragma unroll
        for (int j = 0; j < 4; ++j) {
            if (wa[j] >= 0) {
                const float4* src = reinterpret_cast<const float4*>(
                    fb + (size_t)wa[j] * CD + cb * CBLK);
                float4 a0 = src[0], a1 = src[1], a2 = src[2], a3 = src[3];
                f[j][0]  = a0.x; f[j][1]  = a0.y; f[j][2]  = a0.z; f[j][3]  = a0.w;
                f[j][4]  = a1.x; f[j][5]  = a1.y; f[j][6]  = a1.z; f[j][7]  = a1.w;
                f[j][8]  = a2.x; f[j][9]  = a2.y; f[j][10] = a2.z; f[j][11] = a2.w;
                f[j][12] = a3.x; f[j][13] = a3.y; f[j][14] = a3.z; f[j][15] = a3.w;
            }
        }

#pragma unroll
        for (int c = 0; c < CBLK; ++c) {
            float4 v = make_float4(f[0][c], f[1][c], f[2][c], f[3][c]);
            *reinterpret_cast<float4*>(
                obase + (size_t)(cb * CBLK + c) * NXNY) = v;
        }
    }
}

extern "C" void kernel_launch(void* const* d_in, const int* in_sizes, int n_in,
                              void* d_out, int out_size, void* d_ws, size_t ws_size,
                              hipStream_t stream) {
    const float* feats  = (const float*)d_in[0];   // (B,P,C) fp32
    const int*   coords = (const int*)d_in[1];     // (B,P,3) int32
    float*       out    = (float*)d_out;           // (B,C,NX,NY) fp32
    int*         winner = (int*)d_ws;              // B*NX*NY int32 = 3,936,256 B

    const int init4 = BD * NXNY / 4;               // 246,016 int4 stores
    pp_init_winner<<<(init4 + 255) / 256, 256, 0, stream>>>(winner);

    pp_scatter_idx<<<(BD * PD + 255) / 256, 256, 0, stream>>>(coords, winner);

    const int total = BD * NXD * NY4;              // 246,016 threads
    pp_gather_out<<<(total + 255) / 256, 256, 0, stream>>>(feats, winner, out);
}

// Round 8
// 48.667 us; speedup vs baseline: 1.2395x; 1.0869x over previous
//
#include <hip/hip_runtime.h>

// PointPillarsScatter: scatter (B,P,C) pillar features into a (B,C,NX,NY) BEV grid.
// Duplicate cells: reference scatter-set is last-write-wins over flattened (B*P)
// order => highest p wins per cell.
//
// R7: eliminate the winner-init kernel via a SELF-VALIDATING winner encoding.
// Every v in [0,P) is a real pillar, so a winner entry is trustworthy iff
// coords[b][v] back-points to that exact cell. Scatter uses a CAS loop that
// replaces any non-claimant value (poison, stale) and max-reduces among true
// claimants -> final = max claimant, for ARBITRARY initial ws contents, every
// call (deterministic across graph replays; unoccupied cells keep garbage that
// the gather's back-check rejects). Saves one kernel launch + 3.9 MB fill.
// Gather structure unchanged from R6 (it sits at the ~5.6-5.7 TB/s HBM write
// ceiling: R3/R4/R6 all ~53 us across 4x thread/traffic restructures; nt-store
// bypass regressed -> store stream is the roofline).

#define NXD 496
#define NYD 496
#define CD  64
#define BD  4
#define PD  12000
#define NXNY (NXD * NYD)
#define NY4 (NYD / 4)      // 124
#define CBLK 16            // channels per feats cacheline chunk (64B)
#define NCB (CD / CBLK)    // 4 channel-blocks

// Phase 1: each valid pillar claims its cell. CAS loop semantics:
//   keep old iff old is a genuine claimant of THIS cell and old >= p,
//   else try to install p. Converges to max over claimants regardless of
//   the buffer's initial contents.
__global__ void pp_scatter_idx(const int* __restrict__ coords,
                               int* __restrict__ winner) {
    int tid = blockIdx.x * blockDim.x + threadIdx.x;
    if (tid >= BD * PD) return;
    int b = tid / PD;
    int x = coords[tid * 3 + 1];
    int y = coords[tid * 3 + 2];
    bool valid = (x + y > 0) && (x >= 0) && (x < NXD) && (y >= 0) && (y < NYD);
    if (!valid) return;

    int p = tid - b * PD;
    int* cell = &winner[b * NXNY + x * NYD + y];
    const int* cb = coords + (size_t)b * PD * 3;

    int old = atomicCAS(cell, -1, p);   // fast path if cell held -1; also a load
    while (old != -1) {                 // -1 means our CAS installed p
        bool oldClaims = (old >= 0) && (old < PD) &&
                         (cb[old * 3 + 1] == x) && (cb[old * 3 + 2] == y);
        if (oldClaims && old >= p) break;          // correct winner already there
        int assumed = old;
        old = atomicCAS(cell, assumed, p);
        if (old == assumed) break;                 // installed p; larger claimants
                                                   // will overwrite us via their loop
    }
}

// Phase 2: one thread per {4 consecutive y-cells}, looping all 64 channels.
// Winner entries are validated by back-pointer check (coords[b][v] == cell and
// x+y>0); anything else is "empty" -> zeros. Stores: wave = 1KB contiguous per
// instruction, each c-plane covered densely. Empty-cell zeros double as output
// init over the poisoned d_out.
__global__ void pp_gather_out(const float* __restrict__ feats,
                              const int* __restrict__ coords,
                              const int* __restrict__ winner,
                              float* __restrict__ out) {
    const int total = BD * NXD * NY4;              // 246,016
    int tid = blockIdx.x * blockDim.x + threadIdx.x;
    if (tid >= total) return;

    int y4 = tid % NY4;
    int r  = tid / NY4;
    int x  = r % NXD;
    int b  = r / NXD;
    int y0 = y4 * 4;

    const int4 w = *reinterpret_cast<const int4*>(
        &winner[b * NXNY + x * NYD + y0]);
    int wa[4] = { w.x, w.y, w.z, w.w };

    // Back-pointer validation: v claims cell (x, y0+j) iff coords[b][v]==(x,y)
    // and x+y>0 (cell (0,0) is always invalid per reference).
    const int* cbase = coords + (size_t)b * PD * 3;
#pragma unroll
    for (int j = 0; j < 4; ++j) {
        int v = wa[j];
        bool ok = (v >= 0) && (v < PD);
        if (ok) {
            ok = (cbase[v * 3 + 1] == x) && (cbase[v * 3 + 2] == y0 + j) &&
                 (x + y0 + j > 0);
        }
        wa[j] = ok ? v : -1;
    }

    const float* fb = feats + (size_t)b * PD * CD;
    float* obase = out + (((size_t)b * CD * NXD + x) * NYD + y0);

#pragma unroll
    for (int cb = 0; cb < NCB; ++cb) {
        float f[4][CBLK] = {};   // static-indexed via full unroll -> VGPRs

#pragma unroll
        for (int j = 0; j < 4; ++j) {
            if (wa[j] >= 0) {
                const float4* src = reinterpret_cast<const float4*>(
                    fb + (size_t)wa[j] * CD + cb * CBLK);
                float4 a0 = src[0], a1 = src[1], a2 = src[2], a3 = src[3];
                f[j][0]  = a0.x; f[j][1]  = a0.y; f[j][2]  = a0.z; f[j][3]  = a0.w;
                f[j][4]  = a1.x; f[j][5]  = a1.y; f[j][6]  = a1.z; f[j][7]  = a1.w;
                f[j][8]  = a2.x; f[j][9]  = a2.y; f[j][10] = a2.z; f[j][11] = a2.w;
                f[j][12] = a3.x; f[j][13] = a3.y; f[j][14] = a3.z; f[j][15] = a3.w;
            }
        }

#pragma unroll
        for (int c = 0; c < CBLK; ++c) {
            float4 v = make_float4(f[0][c], f[1][c], f[2][c], f[3][c]);
            *reinterpret_cast<float4*>(
                obase + (size_t)(cb * CBLK + c) * NXNY) = v;
        }
    }
}

extern "C" void kernel_launch(void* const* d_in, const int* in_sizes, int n_in,
                              void* d_out, int out_size, void* d_ws, size_t ws_size,
                              hipStream_t stream) {
    const float* feats  = (const float*)d_in[0];   // (B,P,C) fp32
    const int*   coords = (const int*)d_in[1];     // (B,P,3) int32
    float*       out    = (float*)d_out;           // (B,C,NX,NY) fp32
    int*         winner = (int*)d_ws;              // B*NX*NY int32 = 3,936,256 B

    pp_scatter_idx<<<(BD * PD + 255) / 256, 256, 0, stream>>>(coords, winner);

    const int total = BD * NXD * NY4;              // 246,016 threads
    pp_gather_out<<<(total + 255) / 256, 256, 0, stream>>>(feats, coords, winner, out);
}